// Round 14
// baseline (176.685 us; speedup 1.0000x reference)
//
#include <hip/hip_runtime.h>

#define B_  8
#define C_  128
#define H_  128
#define W_  256
#define HW_ (H_ * W_)
#define TH  8
#define TW  16
#define SROW 392                 // LDS row stride (dw): 24 slots x 16 + 8 pad
#define BUFN 6400                // 16*392 = 6272 + pad for b1 tail reads
#define NTHREADS 512

typedef __fp16 h8 __attribute__((ext_vector_type(8)));
typedef __fp16 h2 __attribute__((ext_vector_type(2)));
typedef float  f4 __attribute__((ext_vector_type(4)));

__device__ __forceinline__ unsigned pk(float x, float y) {
    h2 r = __builtin_amdgcn_cvt_pkrtz(x, y);
    return __builtin_bit_cast(unsigned, r);
}

// Cost volume via MFMA. Per (b, 8h x 16w tile): D[m][ng] = sum_c
// f1[c][h][w0+m] * f2[c][h-4+di][w0-4+ng], band dj = ng-m in [0,8].
// Block = 8 waves, wave = h-row. A (f1) in regs for all K; LDS = f2 only,
// LINEAR layout: row r (16 rows), w-slot s (24 staged of 32), unit u = chan
// group: dw addr = r*392 + s*16 + 4u. No swizzle, no transpose epilogue:
// H0 fragment mapping (col=lane&15, row=4*(lane>>4)+reg) -> direct stores.
__global__ __launch_bounds__(NTHREADS, 2) void cv_kernel(
    const float* __restrict__ f1g, const float* __restrict__ f2g,
    float* __restrict__ outg) {
    __shared__ __align__(16) unsigned lds[2 * BUFN];

    const int tid  = threadIdx.x;
    const int w0   = blockIdx.x * TW;
    const int h0   = blockIdx.y * TH;
    const int b    = blockIdx.z;
    const int wid  = tid >> 6;
    const int lane = tid & 63;
    const int an   = lane & 15;
    const int ag   = lane >> 4;
    const int h    = h0 + wid;

    // ---- staging role (waves 0..5): f2 tile 16r x 24w x 32c per stage ----
    const bool stg = (tid < 384);
    int offS = 0, ldS = 0, uS = 0;
    float mS = 0.f;
    if (stg) {
        int cgS = tid / 96;                // channel-group of 8
        int rem = tid % 96;
        int r = rem / 6;  uS = rem % 6;    // row, w-quad
        int gh = h0 - 4 + r, gw = w0 - 4 + 4 * uS;
        bool valid = (gh >= 0) && (gh < H_) && (gw >= 0) && (gw <= W_ - 4);
        int ghc = min(max(gh, 0), H_ - 1);
        int gwc = min(max(gw, 0), W_ - 4);
        offS = (b * C_ + 8 * cgS) * HW_ + ghc * W_ + gwc;
        ldS  = r * SROW + 4 * cgS;         // + slot*16 added per quad elem
        mS   = valid ? 1.f : 0.f;
    }

    // ---- A fragments: f1[c = 32*kb + 8*ag + i][h][w0+an], in regs ----
    uint4 afr[4];
    {
        int offA = (b * C_ + 8 * ag) * HW_ + h * W_ + w0 + an;
#pragma unroll
        for (int kb = 0; kb < 4; ++kb) {
            float v0 = f1g[offA];            float v1 = f1g[offA + HW_];
            float v2 = f1g[offA + 2 * HW_];  float v3 = f1g[offA + 3 * HW_];
            float v4 = f1g[offA + 4 * HW_];  float v5 = f1g[offA + 5 * HW_];
            float v6 = f1g[offA + 6 * HW_];  float v7 = f1g[offA + 7 * HW_];
            afr[kb] = make_uint4(pk(v0, v1), pk(v2, v3), pk(v4, v5), pk(v6, v7));
            offA += 32 * HW_;
        }
    }

    float4 sA, sB, sC, sD, sE, sF, sG, sH;

#define LOADST()                                                              \
    do { if (stg) {                                                           \
        sA = *(const float4*)(f2g + offS);                                    \
        sB = *(const float4*)(f2g + offS + HW_);                              \
        sC = *(const float4*)(f2g + offS + 2 * HW_);                          \
        sD = *(const float4*)(f2g + offS + 3 * HW_);                          \
        sE = *(const float4*)(f2g + offS + 4 * HW_);                          \
        sF = *(const float4*)(f2g + offS + 5 * HW_);                          \
        sG = *(const float4*)(f2g + offS + 6 * HW_);                          \
        sH = *(const float4*)(f2g + offS + 7 * HW_);                          \
        offS += 32 * HW_;                                                     \
    } } while (0)

#define STQ(bofs, j, c0, c1, c2, c3, c4, c5, c6, c7)                          \
    do {                                                                      \
        uint4 v;                                                              \
        v.x = pk(c0 * mS, c1 * mS); v.y = pk(c2 * mS, c3 * mS);               \
        v.z = pk(c4 * mS, c5 * mS); v.w = pk(c6 * mS, c7 * mS);               \
        *(uint4*)(&lds[(bofs) + ldS + (4 * uS + (j)) * 16]) = v;              \
    } while (0)

#define STOREST(bi)                                                           \
    do { if (stg) {                                                           \
        STQ((bi) * BUFN, 0, sA.x, sB.x, sC.x, sD.x, sE.x, sF.x, sG.x, sH.x);  \
        STQ((bi) * BUFN, 1, sA.y, sB.y, sC.y, sD.y, sE.y, sF.y, sG.y, sH.y);  \
        STQ((bi) * BUFN, 2, sA.z, sB.z, sC.z, sD.z, sE.z, sF.z, sG.z, sH.z);  \
        STQ((bi) * BUFN, 3, sA.w, sB.w, sC.w, sD.w, sE.w, sF.w, sG.w, sH.w);  \
    } } while (0)

#define BAR()                                                                 \
    do {                                                                      \
        asm volatile("s_waitcnt lgkmcnt(0)" ::: "memory");                    \
        __builtin_amdgcn_s_barrier();                                         \
    } while (0)

    f4 acc[9][2];
#pragma unroll
    for (int di = 0; di < 9; ++di) {
        f4 z = {0.f, 0.f, 0.f, 0.f};
        acc[di][0] = z; acc[di][1] = z;
    }

#define COMPUTE(bi, kb)                                                       \
    do {                                                                      \
        const int bo = (bi) * BUFN + an * 16 + 4 * ag;                        \
        _Pragma("unroll")                                                     \
        for (int di = 0; di < 9; ++di) {                                      \
            int ba = bo + (wid + di) * SROW;                                  \
            h8 b0 = *(const h8*)(&lds[ba]);                                   \
            h8 b1 = *(const h8*)(&lds[ba + 256]);                             \
            acc[di][0] = __builtin_amdgcn_mfma_f32_16x16x32_f16(              \
                __builtin_bit_cast(h8, afr[kb]), b0, acc[di][0], 0, 0, 0);    \
            acc[di][1] = __builtin_amdgcn_mfma_f32_16x16x32_f16(              \
                __builtin_bit_cast(h8, afr[kb]), b1, acc[di][1], 0, 0, 0);    \
        }                                                                     \
    } while (0)

    // 4 K-stages, depth-1.5, raw barriers (counted vmcnt on staged loads)
    LOADST(); STOREST(0); BAR();
    LOADST(); COMPUTE(0, 0); STOREST(1); BAR();
    LOADST(); COMPUTE(1, 1); STOREST(0); BAR();
    LOADST(); COMPUTE(0, 2); STOREST(1); BAR();
    COMPUTE(1, 3);

    // ---- epilogue: direct predicated stores (H0 mapping, no transpose) ----
    // lane holds D[m = 4*ag + j][ng = 16*t + an]; dj = ng - m in [0,8].
    const float inv = 1.0f / 128.0f;
    const int m  = 4 * ag;                 // + j
    const int ob = (b * 81 * H_ + h) * W_ + w0 + m;
#pragma unroll
    for (int di = 0; di < 9; ++di) {
#pragma unroll
        for (int t = 0; t < 2; ++t) {
#pragma unroll
            for (int j = 0; j < 4; ++j) {
                int dj = 16 * t + an - m - j;
                if ((unsigned)dj <= 8u) {
                    outg[ob + (di * 9 + dj) * HW_ + j] = acc[di][t][j] * inv;
                }
            }
        }
    }
}

extern "C" void kernel_launch(void* const* d_in, const int* in_sizes, int n_in,
                              void* d_out, int out_size, void* d_ws, size_t ws_size,
                              hipStream_t stream) {
    const float* f1 = (const float*)d_in[0];
    const float* f2 = (const float*)d_in[1];
    float* out = (float*)d_out;
    dim3 grid(W_ / TW, H_ / TH, B_);   // 16 x 16 x 8 = 2048 blocks
    cv_kernel<<<grid, NTHREADS, 0, stream>>>(f1, f2, out);
}